// Round 4
// baseline (3832.988 us; speedup 1.0000x reference)
//
#include <hip/hip_runtime.h>
#include <math.h>

// Problem constants
#define BB 4
#define TT 512
#define FF 257
#define NP 10
#define DM 128
#define C2P 20              // 2*P channels
#define KW 5                // conv taps
#define TP 516              // T padded with 2-row zero halo on each side
#define FROW 320            // feat row stride in floats; word = (f&31)*10 + (f>>5)
#define CHSTRIDE (TP * FROW)        // 165120 floats per channel
#define BSTRIDE (C2P * CHSTRIDE)    // 3302400 floats per batch
#define FSTRIDE (2 * CHSTRIDE)      // per-pair advance (2 channels)

// Workspace (floats): stats @0 (10280) ; wT @10304 (12800) ; feat @23104
// (13,209,600). Total ~50.5 MiB. k1 partials (148,032) OVERLAY feat @23104
// (dead before k2 writes feat).

// ---------------------------------------------------------------------------
// K1a: partial per-(b,f) sums over 32-t chunks, plus the weight transpose
// folded in as 50 extra blocks. wT[(p*10 + r)*128 + d], r = cl*5 + tap.
// partial[(b*257+f)*144 + c*9 + k]: k=0..3 sum_re, 4..7 sum_im, 8 sum_sq
// ---------------------------------------------------------------------------
__global__ __launch_bounds__(256) void k1a_part(const float* __restrict__ x,
                                                float* __restrict__ partial,
                                                const float* __restrict__ convw,
                                                float* __restrict__ wT) {
    const int bid = blockIdx.x;
    if (bid >= BB * 144) {          // ---- weight-transpose blocks ----
        const int idx = (bid - BB * 144) * 256 + threadIdx.x;
        if (idx < NP * 10 * DM) {
            const int p = idx / 1280;
            const int rr = idx - p * 1280;
            const int r = rr >> 7, d = rr & 127;
            const int cl = r / 5, kt = r - cl * 5;
            wT[idx] = convw[(size_t)d * (C2P * KW) + (2 * p + cl) * KW + kt];
        }
        return;
    }
    const int b = bid / 144;
    const int rem = bid - b * 144;
    const int ft = rem >> 4;          // 0..8
    const int c = rem & 15;           // t-chunk 0..15
    const int tid = threadIdx.x;
    const int fi = tid & 31;
    const int th = tid >> 5;          // 0..7
    const int f = ft * 32 + fi;

    float s[9];
    #pragma unroll
    for (int k = 0; k < 9; k++) s[k] = 0.f;
    if (f < FF) {
        #pragma unroll
        for (int q = 0; q < 4; q++) {
            const int t = c * 32 + th * 4 + q;
            const float* px = x + (((size_t)b * TT + t) * FF + f) * 8;
            const float4 v0 = *(const float4*)px;
            const float4 v1 = *(const float4*)(px + 4);
            s[0] += v0.x; s[1] += v0.y; s[2] += v0.z; s[3] += v0.w;
            s[4] += v1.x; s[5] += v1.y; s[6] += v1.z; s[7] += v1.w;
            s[8] += v0.x*v0.x + v0.y*v0.y + v0.z*v0.z + v0.w*v0.w
                  + v1.x*v1.x + v1.y*v1.y + v1.z*v1.z + v1.w*v1.w;
        }
    }
    __shared__ float red[256][9];
    #pragma unroll
    for (int k = 0; k < 9; k++) red[tid][k] = s[k];
    __syncthreads();
    for (int st = 4; st >= 1; st >>= 1) {
        if (th < st) {
            #pragma unroll
            for (int k = 0; k < 9; k++) red[tid][k] += red[tid + 32 * st][k];
        }
        __syncthreads();
    }
    if (th == 0 && f < FF) {
        float* pp = partial + ((size_t)(b * FF + f) * 16 + c) * 9;
        #pragma unroll
        for (int k = 0; k < 9; k++) pp[k] = red[tid][k];
    }
}

// ---------------------------------------------------------------------------
// K1b: finalize stats. One thread per (b,f), spread over 17 blocks (was 4 ->
// latency-bound); partial reads vectorized to 36 float4.
// stats[b][f][10]: 0..3 mean_re, 4..7 mean_im, 8 inv_norm
// ---------------------------------------------------------------------------
__global__ __launch_bounds__(64) void k1b_fin(const float* __restrict__ partial,
                                              float* __restrict__ stats) {
    const int idx = blockIdx.x * 64 + threadIdx.x;
    if (idx >= BB * FF) return;
    const float4* pv = (const float4*)(partial + (size_t)idx * 144);
    float s[9];
    #pragma unroll
    for (int k = 0; k < 9; k++) s[k] = 0.f;
    #pragma unroll
    for (int m = 0; m < 36; m++) {
        const float4 q = pv[m];
        const int base = m * 4;
        s[(base + 0) % 9] += q.x;
        s[(base + 1) % 9] += q.y;
        s[(base + 2) % 9] += q.z;
        s[(base + 3) % 9] += q.w;
    }
    const float invT = 1.0f / (float)TT;
    float pw = s[8] * invT;
    float* st = stats + (size_t)idx * 10;
    #pragma unroll
    for (int m = 0; m < 4; m++) {
        const float mr = s[m] * invT;
        const float mi = s[4 + m] * invT;
        st[m] = mr; st[4 + m] = mi;
        pw -= mr * mr + mi * mi;
    }
    st[8] = rsqrtf(fmaxf(pw, 1e-10f));
}

// ---------------------------------------------------------------------------
// fast atan2: 5-term minimax atan poly on [0,1] (|err| ~1e-5 rad, tolerance
// is 1.6e-2 on the output) + quadrant fixups. Replaces the ~100-instr ocml
// libcall that dominated k2.
// ---------------------------------------------------------------------------
__device__ __forceinline__ float fast_atan2f(float y, float x) {
    const float ax = __builtin_fabsf(x), ay = __builtin_fabsf(y);
    const float mx = fmaxf(ax, ay), mn = fminf(ax, ay);
    const float a = mn * __builtin_amdgcn_rcpf(fmaxf(mx, 1e-35f));
    const float s = a * a;
    float p = fmaf(s, fmaf(s, fmaf(s, fmaf(s, 0.0208351f, -0.0851330f),
                                   0.1801410f), -0.3302995f), 0.9998660f);
    float r = a * p;
    if (ay > ax) r = 1.57079637f - r;
    if (x < 0.f) r = 3.14159274f - r;
    return (y < 0.f) ? -r : r;
}

// ---------------------------------------------------------------------------
// K2: compute SCM features ONCE, stored PRE-SWIZZLED in k3's LDS word order:
// feat[b][ch][tpad][ w=(f&31)*10+(f>>5) ], row stride 320, pad words = 0.
// 320 threads, ONE f per thread (wave-balanced; old version had wave 0 doing
// a second full transcendental pass for f=256 while 255 lanes idled).
// ---------------------------------------------------------------------------
__global__ __launch_bounds__(320) void k2_feat(const float* __restrict__ x,
                                               const float* __restrict__ expnt,
                                               const float* __restrict__ ipdf,
                                               const float* __restrict__ stats,
                                               float* __restrict__ feat) {
    const int b = blockIdx.x / TP;
    const int tpad = blockIdx.x % TP;
    const int t = tpad - 2;
    const int tid = threadIdx.x;
    float* fb = feat + (size_t)b * BSTRIDE + (size_t)tpad * FROW;  // + ch*CHSTRIDE

    if (t < 0 || t >= TT) {          // zero halo rows
        const float4 z = {0.f, 0.f, 0.f, 0.f};
        for (int i = tid; i < C2P * (FROW / 4); i += 320) {
            const int ch = i / (FROW / 4);
            const int w4 = i - ch * (FROW / 4);
            *(float4*)(fb + (size_t)ch * CHSTRIDE + w4 * 4) = z;
        }
        return;
    }

    __shared__ __align__(16) float rows[C2P * FROW];   // 25600 B
    {
        const float4 z = {0.f, 0.f, 0.f, 0.f};
        for (int i = tid; i < C2P * (FROW / 4); i += 320)
            *(float4*)&rows[i * 4] = z;
    }
    __syncthreads();

    if (tid < FF) {
        const int f = tid;
        const float* px = x + (((size_t)b * TT + t) * FF + f) * 8;
        const float4 v0 = *(const float4*)px;
        const float4 v1 = *(const float4*)(px + 4);
        const float* st = stats + ((size_t)b * FF + f) * 10;
        const float inv = st[8];
        float xr[4], xi[4];
        xr[0] = (v0.x - st[0]) * inv; xr[1] = (v0.y - st[1]) * inv;
        xr[2] = (v0.z - st[2]) * inv; xr[3] = (v0.w - st[3]) * inv;
        xi[0] = (v1.x - st[4]) * inv; xi[1] = (v1.y - st[5]) * inv;
        xi[2] = (v1.z - st[6]) * inv; xi[3] = (v1.w - st[7]) * inv;
        const float sef = __builtin_amdgcn_rcpf(1.0f + __expf(-expnt[f]));
        const float sif = __builtin_amdgcn_rcpf(1.0f + __expf(-ipdf[f]));
        const int sw = (f & 31) * 10 + (f >> 5);   // swizzled word within row
        const int MA[NP] = {0,0,0,0,1,1,1,2,2,3};
        const int MB[NP] = {0,1,2,3,1,2,3,2,3,3};
        #pragma unroll
        for (int p = 0; p < NP; p++) {
            const float cra = xr[MA[p]], cia = xi[MA[p]];
            const float crb = xr[MB[p]], cib = xi[MB[p]];
            const float re = cra * crb + cia * cib;
            const float im = cia * crb - cra * cib;
            const float r = sqrtf(re * re + im * im);
            const float bp = exp2f(sef * __log2f(r));   // r=0 -> 0 (matches ref)
            const float a = r * __builtin_amdgcn_rcpf(bp + 1e-10f);
            const float ang = fast_atan2f(im, re) * sif;
            float sn, cs;
            __sincosf(ang, &sn, &cs);
            rows[(2 * p) * FROW + sw] = a * cs;
            rows[(2 * p + 1) * FROW + sw] = a * sn;
        }
    }
    __syncthreads();

    // coalesced write-out: 20 rows x 320 words
    for (int i = tid; i < C2P * (FROW / 4); i += 320) {
        const int ch = i / (FROW / 4);
        const int w4 = i - ch * (FROW / 4);
        *(float4*)(fb + (size_t)ch * CHSTRIDE + w4 * 4) = *(float4*)&rows[ch * FROW + w4 * 4];
    }
}

// ---------------------------------------------------------------------------
// K3: one block per (b,t). Staged GEMM over 10 pairs + fused LayerNorm.
//
// Round-3 post-mortem: LDS instruction pipe was the binding resource
// (10 LDS instrs per 68 FMAs; ~141us/CU floor vs 90us VALU). This version:
//  - retiled 32 f-threads (9 f each, f=ftid+32j) x 16 d-threads (8 d each):
//    acc[8][9]=72 regs, 72 FMAs per r from FIVE LDS instrs (4xb64 + 1xb32,
//    stride-10 swizzle: 2-way bank aliasing = free per m136);
//  - weights read straight from global (L1/L2-resident 51KB, VMEM pipe) ->
//    zero LDS weight traffic, wAll gone;
//  - fbuf LDS-double-buffered with transient regs only (NOT round-2's
//    register dbuf): prefetch at loop top, ds_write after compute, ONE
//    barrier per pair.
// LDS = 25.7KB; VGPR ~115 target (verify <128 & WRITE_SIZE ~275MB).
// ---------------------------------------------------------------------------
__global__ __launch_bounds__(512, 4) void k3_conv_ln(
        const float* __restrict__ feat,
        const float* __restrict__ wT,
        const float* __restrict__ convb,
        const float* __restrict__ lnw,
        const float* __restrict__ lnb,
        float* __restrict__ out) {
    const int bid = blockIdx.x;
    const int bt = (bid & 7) * 256 + (bid >> 3);  // XCD swizzle (2048 % 8 == 0)
    const int b = bt >> 9;
    const int t = bt & 511;
    const int tid = threadIdx.x;
    const int ftid = tid & 31;
    const int dtid = tid >> 5;      // 0..15
    const int d0 = dtid * 8;

    __shared__ __align__(16) float fbuf[2][NP * FROW];  // 2 x 12800 B
    __shared__ float wred[16];

    // staging geometry: 800 float4 per pair = 2 channel-regions x 400
    // (5 contiguous tpad rows t..t+4, already swizzled+padded by k2).
    const size_t gbase = (size_t)b * BSTRIDE + (size_t)t * FROW;
    const int clA = (tid >= 400) ? 1 : 0;
    const int offA = (tid - clA * 400) * 4;       // word offset in region
    const int dstA = clA * (5 * FROW) + offA;
    const bool hasB = (tid < 288);                // 800 - 512 slots
    const int offB = (tid + 512 - 400) * 4;       // region 1 always
    const int dstB = 5 * FROW + offB;

    // prologue: stage pair 0
    {
        const float4 va = *(const float4*)(feat + gbase + (size_t)clA * CHSTRIDE + offA);
        float4 vb;
        if (hasB) vb = *(const float4*)(feat + gbase + CHSTRIDE + offB);
        *(float4*)&fbuf[0][dstA] = va;
        if (hasB) *(float4*)&fbuf[0][dstB] = vb;
    }
    __syncthreads();

    float acc[8][9];
    #pragma unroll
    for (int i = 0; i < 8; i++)
        #pragma unroll
        for (int j = 0; j < 9; j++) acc[i][j] = 0.f;

    #pragma unroll 1
    for (int p = 0; p < NP; p++) {
        // prefetch pair p+1 (transient regs; latency hides under 720 FMAs)
        float4 va, vb;
        if (p < NP - 1) {
            const size_t gp = gbase + (size_t)(p + 1) * FSTRIDE;
            va = *(const float4*)(feat + gp + (size_t)clA * CHSTRIDE + offA);
            if (hasB) vb = *(const float4*)(feat + gp + CHSTRIDE + offB);
        }

        const float* fT = fbuf[p & 1];
        const float* wp = wT + p * 1280 + d0;
        #pragma unroll
        for (int r = 0; r < NP; r++) {
            const float4 w0 = *(const float4*)(wp + r * DM);
            const float4 w1 = *(const float4*)(wp + r * DM + 4);
            const float* bp_ = fT + r * FROW + ftid * 10;
            const float2 q0 = *(const float2*)(bp_ + 0);
            const float2 q1 = *(const float2*)(bp_ + 2);
            const float2 q2 = *(const float2*)(bp_ + 4);
            const float2 q3 = *(const float2*)(bp_ + 6);
            const float fx = bp_[8];    // f = ftid+256: true 0 pad for ftid>0
            const float fv[9] = {q0.x,q0.y,q1.x,q1.y,q2.x,q2.y,q3.x,q3.y,fx};
            const float wa8[8] = {w0.x,w0.y,w0.z,w0.w,w1.x,w1.y,w1.z,w1.w};
            #pragma unroll
            for (int i = 0; i < 8; i++)
                #pragma unroll
                for (int j = 0; j < 9; j++)
                    acc[i][j] = fmaf(wa8[i], fv[j], acc[i][j]);
        }

        if (p < NP - 1) {
            float* nb = fbuf[(p + 1) & 1];
            *(float4*)&nb[dstA] = va;
            if (hasB) *(float4*)&nb[dstB] = vb;
        }
        __syncthreads();    // ONE barrier per pair
    }

    // ---- Epilogue: bias + LayerNorm over (d, f<257), coalesced stores ----
    float cb[8];
    #pragma unroll
    for (int i = 0; i < 8; i++) cb[i] = convb[d0 + i];

    float s1 = 0.f, s2 = 0.f;
    const int jmax = (ftid == 0) ? 9 : 8;     // f = ftid + 32*j < 257
    #pragma unroll
    for (int i = 0; i < 8; i++) {
        #pragma unroll
        for (int j = 0; j < 9; j++) {
            acc[i][j] += cb[i];
            if (j < jmax) { s1 += acc[i][j]; s2 += acc[i][j] * acc[i][j]; }
        }
    }
    #pragma unroll
    for (int off = 32; off >= 1; off >>= 1) {
        s1 += __shfl_down(s1, off, 64);
        s2 += __shfl_down(s2, off, 64);
    }
    const int wv8 = tid >> 6;                 // 8 waves
    if ((tid & 63) == 0) { wred[wv8] = s1; wred[8 + wv8] = s2; }
    __syncthreads();
    float S1 = 0.f, S2 = 0.f;
    #pragma unroll
    for (int w = 0; w < 8; w++) { S1 += wred[w]; S2 += wred[8 + w]; }
    const float Ninv = 1.0f / (float)(DM * FF);
    const float mu = S1 * Ninv;
    const float var = S2 * Ninv - mu * mu;
    const float rstd = rsqrtf(var + 1e-5f);

    float* op = out + (size_t)bt * DM * FF;
    #pragma unroll
    for (int i = 0; i < 8; i++) {
        const int d = d0 + i;
        #pragma unroll
        for (int j = 0; j < 9; j++) {
            const int f = ftid + 32 * j;
            if (f < FF) {
                const size_t o = (size_t)d * FF + f;
                op[o] = (acc[i][j] - mu) * rstd * lnw[o] + lnb[o];
            }
        }
    }
}

extern "C" void kernel_launch(void* const* d_in, const int* in_sizes, int n_in,
                              void* d_out, int out_size, void* d_ws, size_t ws_size,
                              hipStream_t stream) {
    const float* x     = (const float*)d_in[0];
    const float* expnt = (const float*)d_in[1];
    const float* ipdf  = (const float*)d_in[2];
    const float* convw = (const float*)d_in[3];
    const float* convb = (const float*)d_in[4];
    const float* lnw   = (const float*)d_in[5];
    const float* lnb   = (const float*)d_in[6];
    float* out = (float*)d_out;

    // stats 10280 @0 ; wT 12800 @10304 ; feat 13,209,600 @23104  (~50.5 MiB)
    float* stats   = (float*)d_ws;
    float* wT      = stats + 10304;
    float* feat    = stats + 23104;
    float* partial = feat;          // overlay: dead before k2 writes feat

    k1a_part<<<BB * 144 + 50, 256, 0, stream>>>(x, partial, convw, wT);
    k1b_fin<<<17, 64, 0, stream>>>(partial, stats);
    k2_feat<<<BB * TP, 320, 0, stream>>>(x, expnt, ipdf, stats, feat);
    k3_conv_ln<<<BB * TT, 512, 0, stream>>>(feat, wT, convb, lnw, lnb, out);
}